// Round 3
// baseline (109.392 us; speedup 1.0000x reference)
//
#include <hip/hip_runtime.h>

// KPN per-pixel 5x5 predicted convolution, channels-last fp32.
// out[b,h,w,c] = sum_{i,j} feat[b,h+i-2,w+j-2,c] * kernel[b,h,w,i*5+j] + bias[c]
//
// Round 10 = Round 9 + counted-vmcnt two-phase pipeline (T3/T4).
//  - R9 post-mortem: VH 4->8 was neutral => DS model was wrong (TPB=256 is
//    4 waves, not 8; DS ~8.8us/CU, VALU ~3.3us/CU). Kernel slice (~22.5us)
//    vs HBM transfer floor (116 MB -> 18.4us) => HBM-bound with ~4us of
//    EXPOSED staging latency from the monolithic vmcnt(0) drain.
//  - Fix: stage in 2 phases. P1 = weights(oh0..3, 13 issues) + feat rows
//    0..7 (36 issues); P2 = weights(oh4..7, 12) + feat rows 8..11 (18).
//    Per-wave s_waitcnt vmcnt(N), N = compile-time phase-2 outstanding
//    (8/8/7/7), raw s_barrier, compute oh0..3 while P2's 30KB is in
//    flight, then vmcnt(0) + barrier + compute oh4..7.
//  - vmcnt retires in issue order (m135), so "outstanding <= N" proves all
//    P1 loads landed; the lone bias VMEM load cannot violate the bound.
//  - Edge blocks (30%) keep full-drain + OOB zeroing path: zeroing may not
//    race in-flight P2 loads (block-uniform branch, same compute macros).
//  - Phase compute re-reads feat rows 4..7 (+20 b128/thread) — DS is not
//    the critical path, acceptable.

#define BB 4
#define HH 256
#define WW 256
#define CC 32
#define KK 5
#define VH 8                    // output rows per block
#define TW 32                   // tile width (pixels)
#define TPB 256                 // 4 waves
#define TROWS (VH + KK - 1)     // 12 feat rows
#define TCOLS (TW + KK - 1)     // 36 feat cols
#define SF_F4 (TROWS * TCOLS * CC / 4)   // 3456 float4 = 55.3 KB
#define SK_F4 (VH * TW * KK * KK / 4)    // 1600 float4 = 25.6 KB
#define NQ  ((SF_F4 + SK_F4) / 64)       // 79 total issues
#define NQ1 49                  // phase-1 issues: 13 weight + 36 feat

typedef __attribute__((address_space(1))) const void gvoid_t;
typedef __attribute__((address_space(3))) void svoid_t;

__global__ __launch_bounds__(TPB, 2) void kpn_conv_kernel(
    const float* __restrict__ feat,
    const float* __restrict__ kern,
    const float* __restrict__ bias,
    float* __restrict__ out)
{
    __shared__ float4 sb[SF_F4 + SK_F4];   // 80,896 B -> 2 blocks/CU

    const int t    = threadIdx.x;
    const int lane = t & 63;
    const int wave = t >> 6;

    const int bw = blockIdx.x & 7;            // W/TW = 8  (== XCD id)
    const int bh = (blockIdx.x >> 3) & 31;    // H/VH = 32
    const int b  = blockIdx.x >> 8;           // B = 4
    const int h0 = bh * VH;
    const int w0 = bw * TW;

    const float* fb = feat + (((size_t)b) << 16) * CC;
    const float* kb = kern + (size_t)((b * HH + h0) * WW + w0) * (KK * KK);

    // ---- Async staging issue (phase-tagged q ordering). ----
    // q<13: weights kq=q (f4 0..831, covers oh0..3) | q<49: feat fq=q-13
    // (rows 0..7) | q<61: weights kq=q-36 (oh4..7) | else feat fq=q-25
    // (rows 8..11).
    auto issue = [&](int q) {
        if (q < 13 || (q >= NQ1 && q < 61)) {
            int kq  = (q < 13) ? q : q - 36;
            int e   = (kq << 6) + lane;              // 0..1599 exact
            int oh  = e / 200;
            int off = (e - oh * 200) << 2;
            const float* gp = kb + (size_t)oh * (WW * KK * KK) + off;
            __builtin_amdgcn_global_load_lds((gvoid_t*)gp,
                                             (svoid_t*)(sb + SF_F4 + (kq << 6)),
                                             16, 0, 0);
        } else {
            int fq  = (q < NQ1) ? q - 13 : q - 25;   // 0..53
            int e   = (fq << 6) + lane;
            int row = e / (TCOLS * CC / 4);          // /288
            int rem = e - row * (TCOLS * CC / 4);
            int col = rem >> 3;
            int c4  = rem & 7;
            int hc  = min(max(h0 + row - (KK / 2), 0), HH - 1);
            int wc  = min(max(w0 + col - (KK / 2), 0), WW - 1);
            const float* gp = fb + ((((size_t)hc << 8) + wc) << 5) + (c4 << 2);
            __builtin_amdgcn_global_load_lds((gvoid_t*)gp,
                                             (svoid_t*)(sb + (fq << 6)),
                                             16, 0, 0);
        }
    };
    for (int q = wave; q < NQ1; q += TPB / 64) issue(q);        // phase 1
    for (int q = NQ1 + wave; q < NQ; q += TPB / 64) issue(q);   // phase 2
    // Per-wave phase-2 outstanding: wave0:8 wave1:8 wave2:7 wave3:7.

    const int cg = (t & 7) << 2;   // channel group
    const int wL = t >> 3;         // 0..31
    const float* sf  = (const float*)sb;
    const float* skw = (const float*)(sb + SF_F4);

    const float4 bz = *(const float4*)(bias + cg);
    float4 acc[VH];
    #pragma unroll
    for (int oh = 0; oh < VH; ++oh) acc[oh] = bz;

    // 4 output rows (OHB..OHB+3) from 8 feat rows (OHB..OHB+7).
#define COMPUTE_PHASE(OHB)                                                    \
    {                                                                         \
        _Pragma("unroll")                                                     \
        for (int r8 = 0; r8 < 8; ++r8) {                                      \
            const int r = (OHB) + r8;                                         \
            float4 f[KK];                                                     \
            _Pragma("unroll")                                                 \
            for (int j = 0; j < KK; ++j)                                      \
                f[j] = *(const float4*)(sf + (r * TCOLS + wL + j) * CC + cg); \
            _Pragma("unroll")                                                 \
            for (int o4 = 0; o4 < 4; ++o4) {                                  \
                const int i = r8 - o4;                                        \
                if (i >= 0 && i < KK) {                                       \
                    const int oh = (OHB) + o4;                                \
                    const float* wp = skw + (oh * TW + wL) * (KK * KK) + i * KK; \
                    const float wg0 = wp[0], wg1 = wp[1], wg2 = wp[2],        \
                                wg3 = wp[3], wg4 = wp[4];                     \
                    acc[oh].x += f[0].x*wg0 + f[1].x*wg1 + f[2].x*wg2 + f[3].x*wg3 + f[4].x*wg4; \
                    acc[oh].y += f[0].y*wg0 + f[1].y*wg1 + f[2].y*wg2 + f[3].y*wg3 + f[4].y*wg4; \
                    acc[oh].z += f[0].z*wg0 + f[1].z*wg1 + f[2].z*wg2 + f[3].z*wg3 + f[4].z*wg4; \
                    acc[oh].w += f[0].w*wg0 + f[1].w*wg1 + f[2].w*wg2 + f[3].w*wg3 + f[4].w*wg4; \
                }                                                             \
            }                                                                 \
        }                                                                     \
    }

    const bool wlo = (w0 == 0), whi = (w0 == WW - TW);
    const bool edge = (h0 == 0) || (h0 == HH - VH) || wlo || whi;

    if (!edge) {
        // ---- Fast path: counted wait, compute A under phase-2 flight. ----
        if (wave < 2) asm volatile("s_waitcnt vmcnt(8)" ::: "memory");
        else          asm volatile("s_waitcnt vmcnt(7)" ::: "memory");
        __builtin_amdgcn_s_barrier();
        __builtin_amdgcn_sched_barrier(0);
        COMPUTE_PHASE(0);
        asm volatile("s_waitcnt vmcnt(0)" ::: "memory");
        __builtin_amdgcn_s_barrier();
        __builtin_amdgcn_sched_barrier(0);
        COMPUTE_PHASE(4);
    } else {
        // ---- Edge path: full drain, zero OOB halo, then compute. ----
        __syncthreads();   // drains vmcnt(0): all 79 loads landed
        const float4 z = make_float4(0.f, 0.f, 0.f, 0.f);
        #pragma unroll
        for (int r = 0; r < TROWS; ++r) {
            int hraw = h0 + r - (KK / 2);
            if (hraw < 0 || hraw >= HH) {            // uniform per block
                for (int s = t; s < TCOLS * CC / 4; s += TPB)   // 288 slots
                    sb[r * (TCOLS * CC / 4) + s] = z;
            }
        }
        if (wlo && t < 192) {   // cols 0,1: 12 rows x 2 cols x 8 f4
            int r = t >> 4, c = (t >> 3) & 1, c4 = t & 7;
            sb[r * (TCOLS * CC / 4) + c * 8 + c4] = z;
        }
        if (whi && t < 192) {   // cols 34,35
            int r = t >> 4, c = (TCOLS - 2) + ((t >> 3) & 1), c4 = t & 7;
            sb[r * (TCOLS * CC / 4) + c * 8 + c4] = z;
        }
        __syncthreads();
        COMPUTE_PHASE(0);
        COMPUTE_PHASE(4);
    }

    // ---- Coalesced stores: 8 rows x 1 KiB per wave. ----
    #pragma unroll
    for (int oh = 0; oh < VH; ++oh) {
        const size_t pix = (size_t)(b * HH + h0 + oh) * WW + (w0 + wL);
        *(float4*)(out + pix * CC + cg) = acc[oh];
    }
}

extern "C" void kernel_launch(void* const* d_in, const int* in_sizes, int n_in,
                              void* d_out, int out_size, void* d_ws, size_t ws_size,
                              hipStream_t stream) {
    const float* feat = (const float*)d_in[0];
    const float* kern = (const float*)d_in[1];
    const float* bias = (const float*)d_in[2];
    float* out = (float*)d_out;

    dim3 grid(BB * (HH / VH) * (WW / TW));  // 1024 blocks
    dim3 block(TPB);
    kpn_conv_kernel<<<grid, block, 0, stream>>>(feat, kern, bias, out);
}

// Round 5
// 105.140 us; speedup vs baseline: 1.0404x; 1.0404x over previous
//
#include <hip/hip_runtime.h>

// KPN per-pixel 5x5 predicted convolution, channels-last fp32.
// out[b,h,w,c] = sum_{i,j} feat[b,h+i-2,w+j-2,c] * kernel[b,h,w,i*5+j] + bias[c]
//
// Round 12 = Round 11 with the nontemporal-store TYPE fixed (compile error:
// __builtin_nontemporal_store rejects HIP_vector_type float4*; use a native
// clang ext_vector_type(4) float vector, layout-identical).
//
//  - R10 post-mortem: counted-vmcnt 2-phase REGRESSED (109.4): extra DS
//    re-reads + barrier outweighed hidden latency. Reverted (R9 structure).
//  - Three structures (VH4/3blk, VH8/2blk, VH8/2phase) all ~107 => kernel
//    slice (~22.5us) is HBM-transfer-limited, insensitive to scheduling.
//  - Remaining theory: per-XCD L2 (4 MiB) is polluted by 33.5 MB of output
//    write-allocate + 26 MB streaming kern reads, so the vertical-halo
//    feat rows (4/12 staged rows; bw==XCD mapping makes bh-neighbors
//    same-XCD) miss L2 and refetch from HBM (1.69x feat overfetch).
//    Fix: nontemporal out stores (never re-read) => stop write pollution;
//    halo re-reads should become L2 hits.
//  - Predict: feat HBM 56.6 -> ~38 MB, kernel slice -2.5us, dur ~104.
//    If neutral: declare roofline (mixed-R/W BW limit reached).

#define BB 4
#define HH 256
#define WW 256
#define CC 32
#define KK 5
#define VH 8                    // output rows per block
#define TW 32                   // tile width (pixels)
#define TPB 256                 // 4 waves
#define TROWS (VH + KK - 1)     // 12 feat rows
#define TCOLS (TW + KK - 1)     // 36 feat cols
#define SF_F4 (TROWS * TCOLS * CC / 4)   // 3456 float4 = 55.3 KB
#define SK_F4 (VH * TW * KK * KK / 4)    // 1600 float4 = 25.6 KB
#define NQF (SF_F4 / 64)        // 54 feat async issues
#define NQ  ((SF_F4 + SK_F4) / 64)       // 79 total issues

typedef __attribute__((address_space(1))) const void gvoid_t;
typedef __attribute__((address_space(3))) void svoid_t;
typedef float vfloat4 __attribute__((ext_vector_type(4)));   // native vec for nt-store

__global__ __launch_bounds__(TPB, 2) void kpn_conv_kernel(
    const float* __restrict__ feat,
    const float* __restrict__ kern,
    const float* __restrict__ bias,
    float* __restrict__ out)
{
    __shared__ float4 sb[SF_F4 + SK_F4];   // 80,896 B -> 2 blocks/CU

    const int t    = threadIdx.x;
    const int lane = t & 63;
    const int wave = t >> 6;

    const int bw = blockIdx.x & 7;            // W/TW = 8  (== XCD id: vertical
    const int bh = (blockIdx.x >> 3) & 31;    // H/VH = 32  neighbors share L2)
    const int b  = blockIdx.x >> 8;           // B = 4
    const int h0 = bh * VH;
    const int w0 = bw * TW;

    const float* fb = feat + (((size_t)b) << 16) * CC;
    const float* kb = kern + (size_t)((b * HH + h0) * WW + w0) * (KK * KK);

    // ---- Async staging: 79 wave-issues, all in flight, zero VGPR payload. ----
    for (int q = wave; q < NQ; q += TPB / 64) {
        if (q < NQF) {
            // feat: LDS float4 slot e = q*64+lane -> (row, col, c4)
            int e   = (q << 6) + lane;
            int row = e / (TCOLS * CC / 4);          // /288
            int rem = e - row * (TCOLS * CC / 4);
            int col = rem >> 3;
            int c4  = rem & 7;
            int hc  = min(max(h0 + row - (KK / 2), 0), HH - 1);
            int wc  = min(max(w0 + col - (KK / 2), 0), WW - 1);
            const float* gp = fb + ((((size_t)hc << 8) + wc) << 5) + (c4 << 2);
            __builtin_amdgcn_global_load_lds((gvoid_t*)gp,
                                             (svoid_t*)(sb + (q << 6)),
                                             16, 0, 0);
        } else {
            // weights: raw contiguous copy per output row (200 f4 per oh).
            int e   = ((q - NQF) << 6) + lane;       // 0..1599, exact fit
            int oh  = e / 200;
            int off = (e - oh * 200) << 2;
            const float* gp = kb + (size_t)oh * (WW * KK * KK) + off;
            __builtin_amdgcn_global_load_lds((gvoid_t*)gp,
                                             (svoid_t*)(sb + SF_F4 + ((q - NQF) << 6)),
                                             16, 0, 0);
        }
    }
    __syncthreads();   // drains vmcnt (covers global_load_lds)

    // ---- Edge blocks only: zero OOB halo entries (block-uniform branch). ----
    const bool wlo = (w0 == 0), whi = (w0 == WW - TW);
    if (h0 == 0 || h0 == HH - VH || wlo || whi) {
        const float4 z = make_float4(0.f, 0.f, 0.f, 0.f);
        #pragma unroll
        for (int r = 0; r < TROWS; ++r) {
            int hraw = h0 + r - (KK / 2);
            if (hraw < 0 || hraw >= HH) {            // uniform per block
                for (int s = t; s < TCOLS * CC / 4; s += TPB)   // 288 slots
                    sb[r * (TCOLS * CC / 4) + s] = z;
            }
        }
        if (wlo && t < 192) {   // cols 0,1: 12 rows x 2 cols x 8 f4
            int r = t >> 4, c = (t >> 3) & 1, c4 = t & 7;
            sb[r * (TCOLS * CC / 4) + c * 8 + c4] = z;
        }
        if (whi && t < 192) {   // cols 34,35
            int r = t >> 4, c = (TCOLS - 2) + ((t >> 3) & 1), c4 = t & 7;
            sb[r * (TCOLS * CC / 4) + c * 8 + c4] = z;
        }
        __syncthreads();
    }

    // ---- Maskless compute from LDS. ----
    const int cg = (t & 7) << 2;   // channel group
    const int wL = t >> 3;         // 0..31
    const float* sf  = (const float*)sb;
    const float* skw = (const float*)(sb + SF_F4);

    const float4 bz = *(const float4*)(bias + cg);
    float4 acc[VH];
    #pragma unroll
    for (int oh = 0; oh < VH; ++oh) acc[oh] = bz;

    #pragma unroll
    for (int r = 0; r < TROWS; ++r) {
        float4 f[KK];
        #pragma unroll
        for (int j = 0; j < KK; ++j)
            f[j] = *(const float4*)(sf + (r * TCOLS + wL + j) * CC + cg);

        #pragma unroll
        for (int oh = 0; oh < VH; ++oh) {
            const int i = r - oh;                    // kernel row
            if (i >= 0 && i < KK) {                  // compile-time after unroll
                const float* wp = skw + (oh * TW + wL) * (KK * KK) + i * KK;
                const float wg0 = wp[0], wg1 = wp[1], wg2 = wp[2],
                            wg3 = wp[3], wg4 = wp[4];
                acc[oh].x += f[0].x*wg0 + f[1].x*wg1 + f[2].x*wg2 + f[3].x*wg3 + f[4].x*wg4;
                acc[oh].y += f[0].y*wg0 + f[1].y*wg1 + f[2].y*wg2 + f[3].y*wg3 + f[4].y*wg4;
                acc[oh].z += f[0].z*wg0 + f[1].z*wg1 + f[2].z*wg2 + f[3].z*wg3 + f[4].z*wg4;
                acc[oh].w += f[0].w*wg0 + f[1].w*wg1 + f[2].w*wg2 + f[3].w*wg3 + f[4].w*wg4;
            }
        }
    }

    // ---- Coalesced NONTEMPORAL stores: 8 rows x 1 KiB per wave. ----
    // out is never re-read; nt keeps 33.5 MB of write data from evicting
    // feat halo lines in the per-XCD L2.
    #pragma unroll
    for (int oh = 0; oh < VH; ++oh) {
        const size_t pix = (size_t)(b * HH + h0 + oh) * WW + (w0 + wL);
        vfloat4 v = { acc[oh].x, acc[oh].y, acc[oh].z, acc[oh].w };
        __builtin_nontemporal_store(v, (vfloat4*)(out + pix * CC + cg));
    }
}

extern "C" void kernel_launch(void* const* d_in, const int* in_sizes, int n_in,
                              void* d_out, int out_size, void* d_ws, size_t ws_size,
                              hipStream_t stream) {
    const float* feat = (const float*)d_in[0];
    const float* kern = (const float*)d_in[1];
    const float* bias = (const float*)d_in[2];
    float* out = (float*)d_out;

    dim3 grid(BB * (HH / VH) * (WW / TW));  // 1024 blocks
    dim3 block(TPB);
    kpn_conv_kernel<<<grid, block, 0, stream>>>(feat, kern, bias, out);
}